// Round 1
// baseline (3257.448 us; speedup 1.0000x reference)
//
#include <hip/hip_runtime.h>

#define NV 100000
#define NC 100000
#define NSOC 20000
#define EVC 2000000
#define ESC 300000
#define H 64

constexpr int NPW = 16;   // nodes per wave in gemm kernels
constexpr int EPW = 8;    // edges per wave in scatter kernel
constexpr int OPW = 16;   // nodes per wave in output kernel

// ---------------------------------------------------------------------------
// Fused GEMM: out[n][j] = act( s1*(dot(X1[n],W1[:,j]) + bias[j])
//                              + [NSEC>=1] dot(X2a[n] (+X2b[n]), W2[:,j]) )
// One wave (64 lanes) = 64 output columns; each wave handles NPW rows.
// Weight columns live in VGPRs; X rows are wave-uniform -> scalar loads.
// ---------------------------------------------------------------------------
template<int K1, bool RELU, int NSEC>
__global__ __launch_bounds__(256) void gemmK(
    const float* __restrict__ X1, const float* __restrict__ W1,
    const float* __restrict__ X2a, const float* __restrict__ X2b,
    const float* __restrict__ W2,
    const float* __restrict__ bias, float* __restrict__ out,
    int N, float s1)
{
  const int lane = threadIdx.x & 63;
  const int wave = __builtin_amdgcn_readfirstlane(blockIdx.x * 4 + (threadIdx.x >> 6));

  float w1[K1];
#pragma unroll
  for (int k = 0; k < K1; ++k) w1[k] = W1[k * H + lane];

  float w2[NSEC > 0 ? H : 1];
  if constexpr (NSEC > 0) {
#pragma unroll
    for (int k = 0; k < H; ++k) w2[k] = W2[k * H + lane];
  }
  const float bj = bias[lane];

  const int n0 = wave * NPW;
  for (int i = 0; i < NPW; ++i) {
    const int n = n0 + i;
    if (n >= N) break;

    float acc;
    if constexpr (K1 == H) {
      const float4* x4 = reinterpret_cast<const float4*>(X1 + (size_t)n * H);
      float a0 = 0.f, a1 = 0.f, a2 = 0.f, a3 = 0.f;
#pragma unroll
      for (int k4 = 0; k4 < H / 4; ++k4) {
        const float4 xv = x4[k4];
        a0 = fmaf(xv.x, w1[4 * k4 + 0], a0);
        a1 = fmaf(xv.y, w1[4 * k4 + 1], a1);
        a2 = fmaf(xv.z, w1[4 * k4 + 2], a2);
        a3 = fmaf(xv.w, w1[4 * k4 + 3], a3);
      }
      acc = (a0 + a1) + (a2 + a3);
    } else {
      const float* x1 = X1 + (size_t)n * K1;
      acc = 0.f;
#pragma unroll
      for (int k = 0; k < K1; ++k) acc = fmaf(x1[k], w1[k], acc);
    }
    acc = s1 * (acc + bj);

    if constexpr (NSEC > 0) {
      float a0 = 0.f, a1 = 0.f, a2 = 0.f, a3 = 0.f;
      const float4* xa = reinterpret_cast<const float4*>(X2a + (size_t)n * H);
#pragma unroll
      for (int k4 = 0; k4 < H / 4; ++k4) {
        const float4 xv = xa[k4];
        a0 = fmaf(xv.x, w2[4 * k4 + 0], a0);
        a1 = fmaf(xv.y, w2[4 * k4 + 1], a1);
        a2 = fmaf(xv.z, w2[4 * k4 + 2], a2);
        a3 = fmaf(xv.w, w2[4 * k4 + 3], a3);
      }
      if constexpr (NSEC == 2) {
        const float4* xb = reinterpret_cast<const float4*>(X2b + (size_t)n * H);
#pragma unroll
        for (int k4 = 0; k4 < H / 4; ++k4) {
          const float4 xv = xb[k4];
          a0 = fmaf(xv.x, w2[4 * k4 + 0], a0);
          a1 = fmaf(xv.y, w2[4 * k4 + 1], a1);
          a2 = fmaf(xv.z, w2[4 * k4 + 2], a2);
          a3 = fmaf(xv.w, w2[4 * k4 + 3], a3);
        }
      }
      acc += (a0 + a1) + (a2 + a3);
    }

    if constexpr (RELU) acc = fmaxf(acc, 0.f);
    out[(size_t)n * H + lane] = acc;
  }
}

// ---------------------------------------------------------------------------
// Scatter segment-max: agg[dst[e]][j] = max(agg, pooled[src[e]][j]).
// pooled is post-ReLU (>=0) so uint bit-pattern atomicMax is exact and the
// zero-init matches DGL's zero-in-degree -> 0 semantics. Skip v==0 atomics.
// ---------------------------------------------------------------------------
__global__ __launch_bounds__(256) void scatter_max_k(
    const float* __restrict__ pooled, const int* __restrict__ src,
    const int* __restrict__ dst, unsigned int* __restrict__ agg, int E)
{
  const int lane = threadIdx.x & 63;
  const int wave = __builtin_amdgcn_readfirstlane(blockIdx.x * 4 + (threadIdx.x >> 6));
  const int e0 = wave * EPW;
  for (int i = 0; i < EPW; ++i) {
    const int e = e0 + i;
    if (e >= E) break;
    const int s = src[e];
    const int d = dst[e];
    const float v = pooled[(size_t)s * H + lane];
    if (v > 0.f) atomicMax(agg + (size_t)d * H + lane, __float_as_uint(v));
  }
}

// ---------------------------------------------------------------------------
// Output head: out[n] = dot(Z[n], Wout) + bout. One wave per row group.
// ---------------------------------------------------------------------------
__global__ __launch_bounds__(256) void out_k(
    const float* __restrict__ Z, const float* __restrict__ Wout,
    const float* __restrict__ bout, float* __restrict__ out, int N)
{
  const int lane = threadIdx.x & 63;
  const int wave = __builtin_amdgcn_readfirstlane(blockIdx.x * 4 + (threadIdx.x >> 6));
  const float w = Wout[lane];
  const float b = bout[0];
  const int n0 = wave * OPW;
  for (int i = 0; i < OPW; ++i) {
    const int n = n0 + i;
    if (n >= N) break;
    float v = Z[(size_t)n * H + lane] * w;
#pragma unroll
    for (int off = 32; off; off >>= 1) v += __shfl_down(v, off);
    if (lane == 0) out[n] = v + b;
  }
}

extern "C" void kernel_launch(void* const* d_in, const int* in_sizes, int n_in,
                              void* d_out, int out_size, void* d_ws, size_t ws_size,
                              hipStream_t stream) {
  const float* var_x = (const float*)d_in[0];
  const float* con_x = (const float*)d_in[1];
  const float* soc_x = (const float*)d_in[2];
  const float* W_var = (const float*)d_in[3];
  const float* b_var = (const float*)d_in[4];
  const float* W_con = (const float*)d_in[5];
  const float* b_con = (const float*)d_in[6];
  const float* W_soc = (const float*)d_in[7];
  const float* b_soc = (const float*)d_in[8];
  // L[0]=l1f, L[1]=l1b, L[2]=l2f, L[3]=l2b ; p: 0=Wp 1=bp 2=Ws 3=Wn 4=b
  const float* L[4][5];
  for (int l = 0; l < 4; ++l)
    for (int p = 0; p < 5; ++p)
      L[l][p] = (const float*)d_in[9 + l * 5 + p];
  const float* W_hid = (const float*)d_in[29];
  const float* b_hid = (const float*)d_in[30];
  const float* W_out = (const float*)d_in[31];
  const float* b_out = (const float*)d_in[32];
  const int* vc_src = (const int*)d_in[33];
  const int* vc_dst = (const int*)d_in[34];
  const int* sc_src = (const int*)d_in[35];
  const int* sc_dst = (const int*)d_in[36];

  const size_t BIG = (size_t)NV * H * sizeof(float);   // 25.6 MB
  const size_t SOC = (size_t)NSOC * H * sizeof(float); // 5.12 MB
  char* ws = (char*)d_ws;
  float* h_var   = (float*)(ws + 0 * BIG);
  float* h_var2  = (float*)(ws + 1 * BIG);
  float* h_con   = (float*)(ws + 2 * BIG);
  float* h_con2  = (float*)(ws + 3 * BIG);
  float* pooledB = (float*)(ws + 4 * BIG);
  float* agg_a   = (float*)(ws + 5 * BIG);
  float* agg_b   = (float*)(ws + 6 * BIG);
  float* h_soc   = (float*)(ws + 7 * BIG);
  float* h_soc2  = (float*)(ws + 7 * BIG + SOC);
  float* pooledS = (float*)(ws + 7 * BIG + 2 * SOC);

  auto grid_n = [](int n) { return dim3((unsigned)((n + 4 * NPW - 1) / (4 * NPW))); };
  auto grid_e = [](int e) { return dim3((unsigned)((e + 4 * EPW - 1) / (4 * EPW))); };
  const dim3 B(256);

  // ---- embeddings -------------------------------------------------------
  gemmK<7, true, 0><<<grid_n(NV), B, 0, stream>>>(var_x, W_var, nullptr, nullptr, nullptr, b_var, h_var, NV, 1.f);
  gemmK<4, true, 0><<<grid_n(NC), B, 0, stream>>>(con_x, W_con, nullptr, nullptr, nullptr, b_con, h_con, NC, 1.f);
  gemmK<6, true, 0><<<grid_n(NSOC), B, 0, stream>>>(soc_x, W_soc, nullptr, nullptr, nullptr, b_soc, h_soc, NSOC, 1.f);

  // ---- forward half-passes (update constraints) -------------------------
  float* cin = h_con;
  float* cout = h_con2;
  auto fwd_layer = [&](int li) {
    gemmK<64, true, 0><<<grid_n(NV), B, 0, stream>>>(h_var, L[li][0], nullptr, nullptr, nullptr, L[li][1], pooledB, NV, 1.f);
    gemmK<64, true, 0><<<grid_n(NSOC), B, 0, stream>>>(h_soc, L[li][0], nullptr, nullptr, nullptr, L[li][1], pooledS, NSOC, 1.f);
    hipMemsetAsync(agg_a, 0, BIG, stream);
    hipMemsetAsync(agg_b, 0, BIG, stream);
    scatter_max_k<<<grid_e(EVC), B, 0, stream>>>(pooledB, vc_src, vc_dst, (unsigned int*)agg_a, EVC);
    scatter_max_k<<<grid_e(ESC), B, 0, stream>>>(pooledS, sc_src, sc_dst, (unsigned int*)agg_b, ESC);
    // h_con_new = relu(2*(h_con@Ws + b) + (agg_v+agg_s)@Wn)
    gemmK<64, true, 2><<<grid_n(NC), B, 0, stream>>>(cin, L[li][2], agg_a, agg_b, L[li][3], L[li][4], cout, NC, 2.f);
    float* t = cin; cin = cout; cout = t;
  };
  fwd_layer(0);  // l1f
  fwd_layer(2);  // l2f
  // cin now == h_con (final constraint embeddings)

  // ---- backward half-passes (update var & soc from final h_con) ---------
  float* vin = h_var;  float* vout = h_var2;
  float* sin_ = h_soc; float* sout = h_soc2;
  auto bwd_layer = [&](int li) {
    gemmK<64, true, 0><<<grid_n(NC), B, 0, stream>>>(cin, L[li][0], nullptr, nullptr, nullptr, L[li][1], pooledB, NC, 1.f);
    hipMemsetAsync(agg_a, 0, BIG, stream);
    hipMemsetAsync(agg_b, 0, SOC, stream);
    // reversed edges: gather pooled at vc_dst, scatter-max into vc_src
    scatter_max_k<<<grid_e(EVC), B, 0, stream>>>(pooledB, vc_dst, vc_src, (unsigned int*)agg_a, EVC);
    scatter_max_k<<<grid_e(ESC), B, 0, stream>>>(pooledB, sc_dst, sc_src, (unsigned int*)agg_b, ESC);
    gemmK<64, true, 1><<<grid_n(NV), B, 0, stream>>>(vin, L[li][2], agg_a, nullptr, L[li][3], L[li][4], vout, NV, 1.f);
    gemmK<64, true, 1><<<grid_n(NSOC), B, 0, stream>>>(sin_, L[li][2], agg_b, nullptr, L[li][3], L[li][4], sout, NSOC, 1.f);
    float* t = vin; vin = vout; vout = t;
    t = sin_; sin_ = sout; sout = t;
  };
  bwd_layer(1);  // l1b
  bwd_layer(3);  // l2b
  // vin now == final h_var

  // ---- output MLP (shared Linear applied twice, then head) --------------
  gemmK<64, true, 0><<<grid_n(NV), B, 0, stream>>>(vin, W_hid, nullptr, nullptr, nullptr, b_hid, pooledB, NV, 1.f);
  gemmK<64, true, 0><<<grid_n(NV), B, 0, stream>>>(pooledB, W_hid, nullptr, nullptr, nullptr, b_hid, agg_a, NV, 1.f);
  out_k<<<dim3((unsigned)((NV + 4 * OPW - 1) / (4 * OPW))), B, 0, stream>>>(agg_a, W_out, b_out, (float*)d_out, NV);
}

// Round 2
// 1824.801 us; speedup vs baseline: 1.7851x; 1.7851x over previous
//
#include <hip/hip_runtime.h>

#define NV 100000
#define NC 100000
#define NSOC 20000
#define EVC 2000000
#define ESC 300000
#define H 64

constexpr int NPW = 16;   // nodes per wave in gemm kernels
constexpr int OPW = 16;   // nodes per wave in output kernel

// ---------------------------------------------------------------------------
// Fused GEMM: out[n][j] = act( s1*(dot(X1[n],W1[:,j]) + bias[j])
//                              + [NSEC>=1] dot(X2a[n] (+X2b[n]), W2[:,j]) )
// One wave = 64 output columns; 2-row ILP for latency hiding.
// ---------------------------------------------------------------------------
template<int K1, bool RELU, int NSEC>
__global__ __launch_bounds__(256) void gemmK(
    const float* __restrict__ X1, const float* __restrict__ W1,
    const float* __restrict__ X2a, const float* __restrict__ X2b,
    const float* __restrict__ W2,
    const float* __restrict__ bias, float* __restrict__ out,
    int N, float s1)
{
  const int lane = threadIdx.x & 63;
  const int wave = __builtin_amdgcn_readfirstlane(blockIdx.x * 4 + (threadIdx.x >> 6));

  float w1[K1];
#pragma unroll
  for (int k = 0; k < K1; ++k) w1[k] = W1[k * H + lane];

  float w2[NSEC > 0 ? H : 1];
  if constexpr (NSEC > 0) {
#pragma unroll
    for (int k = 0; k < H; ++k) w2[k] = W2[k * H + lane];
  }
  const float bj = bias[lane];

  const int n0 = wave * NPW;
  for (int i = 0; i < NPW; i += 2) {
    const int na = n0 + i;
    if (na >= N) break;
    const bool wb = (na + 1) < N;
    const int nb = wb ? na + 1 : na;

    float accA, accB;
    if constexpr (K1 == H) {
      const float4* xa = reinterpret_cast<const float4*>(X1 + (size_t)na * H);
      const float4* xb = reinterpret_cast<const float4*>(X1 + (size_t)nb * H);
      float a0 = 0.f, a1 = 0.f, a2 = 0.f, a3 = 0.f;
      float b0 = 0.f, b1 = 0.f, b2 = 0.f, b3 = 0.f;
#pragma unroll
      for (int k4 = 0; k4 < H / 4; ++k4) {
        const float4 va = xa[k4];
        const float4 vb = xb[k4];
        a0 = fmaf(va.x, w1[4 * k4 + 0], a0);
        b0 = fmaf(vb.x, w1[4 * k4 + 0], b0);
        a1 = fmaf(va.y, w1[4 * k4 + 1], a1);
        b1 = fmaf(vb.y, w1[4 * k4 + 1], b1);
        a2 = fmaf(va.z, w1[4 * k4 + 2], a2);
        b2 = fmaf(vb.z, w1[4 * k4 + 2], b2);
        a3 = fmaf(va.w, w1[4 * k4 + 3], a3);
        b3 = fmaf(vb.w, w1[4 * k4 + 3], b3);
      }
      accA = (a0 + a1) + (a2 + a3);
      accB = (b0 + b1) + (b2 + b3);
    } else {
      const float* xa = X1 + (size_t)na * K1;
      const float* xb = X1 + (size_t)nb * K1;
      accA = 0.f; accB = 0.f;
#pragma unroll
      for (int k = 0; k < K1; ++k) {
        accA = fmaf(xa[k], w1[k], accA);
        accB = fmaf(xb[k], w1[k], accB);
      }
    }
    accA = s1 * (accA + bj);
    accB = s1 * (accB + bj);

    if constexpr (NSEC > 0) {
      float a0 = 0.f, a1 = 0.f, a2 = 0.f, a3 = 0.f;
      float b0 = 0.f, b1 = 0.f, b2 = 0.f, b3 = 0.f;
      const float4* xa = reinterpret_cast<const float4*>(X2a + (size_t)na * H);
      const float4* xb = reinterpret_cast<const float4*>(X2a + (size_t)nb * H);
#pragma unroll
      for (int k4 = 0; k4 < H / 4; ++k4) {
        const float4 va = xa[k4];
        const float4 vb = xb[k4];
        a0 = fmaf(va.x, w2[4 * k4 + 0], a0);
        b0 = fmaf(vb.x, w2[4 * k4 + 0], b0);
        a1 = fmaf(va.y, w2[4 * k4 + 1], a1);
        b1 = fmaf(vb.y, w2[4 * k4 + 1], b1);
        a2 = fmaf(va.z, w2[4 * k4 + 2], a2);
        b2 = fmaf(vb.z, w2[4 * k4 + 2], b2);
        a3 = fmaf(va.w, w2[4 * k4 + 3], a3);
        b3 = fmaf(vb.w, w2[4 * k4 + 3], b3);
      }
      if constexpr (NSEC == 2) {
        const float4* ya = reinterpret_cast<const float4*>(X2b + (size_t)na * H);
        const float4* yb = reinterpret_cast<const float4*>(X2b + (size_t)nb * H);
#pragma unroll
        for (int k4 = 0; k4 < H / 4; ++k4) {
          const float4 va = ya[k4];
          const float4 vb = yb[k4];
          a0 = fmaf(va.x, w2[4 * k4 + 0], a0);
          b0 = fmaf(vb.x, w2[4 * k4 + 0], b0);
          a1 = fmaf(va.y, w2[4 * k4 + 1], a1);
          b1 = fmaf(vb.y, w2[4 * k4 + 1], b1);
          a2 = fmaf(va.z, w2[4 * k4 + 2], a2);
          b2 = fmaf(vb.z, w2[4 * k4 + 2], b2);
          a3 = fmaf(va.w, w2[4 * k4 + 3], a3);
          b3 = fmaf(vb.w, w2[4 * k4 + 3], b3);
        }
      }
      accA += (a0 + a1) + (a2 + a3);
      accB += (b0 + b1) + (b2 + b3);
    }

    if constexpr (RELU) { accA = fmaxf(accA, 0.f); accB = fmaxf(accB, 0.f); }
    out[(size_t)na * H + lane] = accA;
    if (wb) out[(size_t)nb * H + lane] = accB;
  }
}

// ---------------------------------------------------------------------------
// CSR build: histogram -> 2-level exclusive scan -> fill (payload = other end)
// ---------------------------------------------------------------------------
__global__ __launch_bounds__(256) void hist_k(const int* __restrict__ key,
                                              int* __restrict__ deg, int E) {
  int i = blockIdx.x * 256 + threadIdx.x;
  if (i < E) atomicAdd(&deg[key[i]], 1);
}

__global__ __launch_bounds__(256) void scan1_k(const int* __restrict__ deg,
                                               int* __restrict__ bsum, int N) {
  __shared__ int s[256];
  const int t = threadIdx.x;
  const int gi = blockIdx.x * 256 + t;
  s[t] = (gi < N) ? deg[gi] : 0;
  __syncthreads();
  for (int off = 128; off; off >>= 1) {
    if (t < off) s[t] += s[t + off];
    __syncthreads();
  }
  if (t == 0) bsum[blockIdx.x] = s[0];
}

__global__ __launch_bounds__(512) void scan2_k(const int* __restrict__ bsum,
                                               int* __restrict__ bofs, int NB) {
  __shared__ int s[512];
  const int t = threadIdx.x;
  const int v = (t < NB) ? bsum[t] : 0;
  s[t] = v;
  __syncthreads();
  for (int off = 1; off < 512; off <<= 1) {
    int x = (t >= off) ? s[t - off] : 0;
    __syncthreads();
    s[t] += x;
    __syncthreads();
  }
  if (t < NB) bofs[t] = s[t] - v;  // exclusive
}

__global__ __launch_bounds__(256) void scan3_k(const int* __restrict__ deg,
                                               const int* __restrict__ bofs,
                                               int* __restrict__ rp, int N) {
  __shared__ int s[256];
  const int t = threadIdx.x;
  const int gi = blockIdx.x * 256 + t;
  const int v = (gi < N) ? deg[gi] : 0;
  s[t] = v;
  __syncthreads();
  for (int off = 1; off < 256; off <<= 1) {
    int x = (t >= off) ? s[t - off] : 0;
    __syncthreads();
    s[t] += x;
    __syncthreads();
  }
  const int incl = s[t];
  const int base = bofs[blockIdx.x];
  if (gi < N) rp[gi] = base + incl - v;
  if (gi == N - 1) rp[N] = base + incl;
}

__global__ __launch_bounds__(256) void fill_k(const int* __restrict__ key,
                                              const int* __restrict__ payload,
                                              const int* __restrict__ rp,
                                              int* __restrict__ cur,
                                              int* __restrict__ ei, int E) {
  int i = blockIdx.x * 256 + threadIdx.x;
  if (i < E) {
    const int d = key[i];
    const int p = atomicAdd(&cur[d], 1);
    ei[rp[d] + p] = payload[i];
  }
}

// ---------------------------------------------------------------------------
// CSR gather segment-max: one wave per dst node; lane = feature.
// agg init 0 matches DGL zero-in-degree semantics (pooled >= 0 post-ReLU).
// ---------------------------------------------------------------------------
__global__ __launch_bounds__(256) void gather_max_k(
    const float* __restrict__ pooled, const int* __restrict__ rp,
    const int* __restrict__ ei, float* __restrict__ out, int N)
{
  const int lane = threadIdx.x & 63;
  const int n = __builtin_amdgcn_readfirstlane(blockIdx.x * 4 + (threadIdx.x >> 6));
  if (n >= N) return;
  const int p0 = rp[n];
  const int p1 = rp[n + 1];
  float m = 0.f;
  for (int p = p0; p < p1; ++p) {
    const int s = ei[p];
    m = fmaxf(m, pooled[(size_t)s * H + lane]);
  }
  out[(size_t)n * H + lane] = m;
}

// ---------------------------------------------------------------------------
// Output head: out[n] = dot(Z[n], Wout) + bout.
// ---------------------------------------------------------------------------
__global__ __launch_bounds__(256) void out_k(
    const float* __restrict__ Z, const float* __restrict__ Wout,
    const float* __restrict__ bout, float* __restrict__ out, int N)
{
  const int lane = threadIdx.x & 63;
  const int wave = __builtin_amdgcn_readfirstlane(blockIdx.x * 4 + (threadIdx.x >> 6));
  const float w = Wout[lane];
  const float b = bout[0];
  const int n0 = wave * OPW;
  for (int i = 0; i < OPW; ++i) {
    const int n = n0 + i;
    if (n >= N) break;
    float v = Z[(size_t)n * H + lane] * w;
#pragma unroll
    for (int off = 32; off; off >>= 1) v += __shfl_down(v, off);
    if (lane == 0) out[n] = v + b;
  }
}

extern "C" void kernel_launch(void* const* d_in, const int* in_sizes, int n_in,
                              void* d_out, int out_size, void* d_ws, size_t ws_size,
                              hipStream_t stream) {
  const float* var_x = (const float*)d_in[0];
  const float* con_x = (const float*)d_in[1];
  const float* soc_x = (const float*)d_in[2];
  const float* W_var = (const float*)d_in[3];
  const float* b_var = (const float*)d_in[4];
  const float* W_con = (const float*)d_in[5];
  const float* b_con = (const float*)d_in[6];
  const float* W_soc = (const float*)d_in[7];
  const float* b_soc = (const float*)d_in[8];
  const float* L[4][5];  // L[0]=l1f, L[1]=l1b, L[2]=l2f, L[3]=l2b
  for (int l = 0; l < 4; ++l)
    for (int p = 0; p < 5; ++p)
      L[l][p] = (const float*)d_in[9 + l * 5 + p];
  const float* W_hid = (const float*)d_in[29];
  const float* b_hid = (const float*)d_in[30];
  const float* W_out = (const float*)d_in[31];
  const float* b_out = (const float*)d_in[32];
  const int* vc_src = (const int*)d_in[33];
  const int* vc_dst = (const int*)d_in[34];
  const int* sc_src = (const int*)d_in[35];
  const int* sc_dst = (const int*)d_in[36];

  const size_t BIG = (size_t)NV * H * sizeof(float);   // 25.6 MB
  const size_t SOC = (size_t)NSOC * H * sizeof(float); // 5.12 MB
  const size_t RPB = ((size_t)(NV + 2) * 4 + 255) & ~255ull;  // rowptr buf
  char* ws = (char*)d_ws;
  float* h_var   = (float*)(ws + 0 * BIG);
  float* h_var2  = (float*)(ws + 1 * BIG);
  float* h_con   = (float*)(ws + 2 * BIG);
  float* h_con2  = (float*)(ws + 3 * BIG);
  float* pooledB = (float*)(ws + 4 * BIG);
  float* agg_a   = (float*)(ws + 5 * BIG);
  float* agg_b   = (float*)(ws + 6 * BIG);
  float* h_soc   = (float*)(ws + 7 * BIG);
  float* h_soc2  = (float*)(ws + 7 * BIG + SOC);
  float* pooledS = (float*)(ws + 7 * BIG + 2 * SOC);
  char* csr = ws + 7 * BIG + 3 * SOC;
  int* rpA  = (int*)(csr);                    // rowptr, big relation
  int* eiA  = (int*)(csr + RPB);              // edge payloads, EVC ints
  int* rpB  = (int*)(csr + RPB + (size_t)EVC * 4);
  int* eiB  = (int*)(csr + 2 * RPB + (size_t)EVC * 4);
  char* aux = csr + 2 * RPB + (size_t)(EVC + ESC) * 4;
  int* deg  = (int*)(aux);
  int* cur  = (int*)(aux + RPB);
  int* bsum = (int*)(aux + 2 * RPB);
  int* bofs = (int*)(aux + 2 * RPB + 4096);

  auto grid_n = [](int n) { return dim3((unsigned)((n + 4 * NPW - 1) / (4 * NPW))); };
  auto grid_t = [](int n) { return dim3((unsigned)((n + 255) / 256)); };
  auto grid_w = [](int n) { return dim3((unsigned)((n + 3) / 4)); };
  const dim3 B(256);

  // builds CSR (rowptr rp, payload ei) keyed on `key`, NB = #nodes
  auto build_csr = [&](const int* key, const int* payload, int E, int Nn,
                       int* rp, int* ei) {
    const int nb = (Nn + 255) / 256;
    hipMemsetAsync(deg, 0, (size_t)Nn * 4, stream);
    hist_k<<<grid_t(E), B, 0, stream>>>(key, deg, E);
    scan1_k<<<dim3((unsigned)nb), B, 0, stream>>>(deg, bsum, Nn);
    scan2_k<<<dim3(1), dim3(512), 0, stream>>>(bsum, bofs, nb);
    scan3_k<<<dim3((unsigned)nb), B, 0, stream>>>(deg, bofs, rp, Nn);
    hipMemsetAsync(cur, 0, (size_t)Nn * 4, stream);
    fill_k<<<grid_t(E), B, 0, stream>>>(key, payload, rp, cur, ei, E);
  };

  // ---- embeddings -------------------------------------------------------
  gemmK<7, true, 0><<<grid_n(NV), B, 0, stream>>>(var_x, W_var, nullptr, nullptr, nullptr, b_var, h_var, NV, 1.f);
  gemmK<4, true, 0><<<grid_n(NC), B, 0, stream>>>(con_x, W_con, nullptr, nullptr, nullptr, b_con, h_con, NC, 1.f);
  gemmK<6, true, 0><<<grid_n(NSOC), B, 0, stream>>>(soc_x, W_soc, nullptr, nullptr, nullptr, b_soc, h_soc, NSOC, 1.f);

  // ---- CSR by destination (constraints) ---------------------------------
  build_csr(vc_dst, vc_src, EVC, NC, rpA, eiA);
  build_csr(sc_dst, sc_src, ESC, NC, rpB, eiB);

  // ---- forward half-passes (update constraints) -------------------------
  float* cin = h_con;
  float* cout = h_con2;
  auto fwd_layer = [&](int li) {
    gemmK<64, true, 0><<<grid_n(NV), B, 0, stream>>>(h_var, L[li][0], nullptr, nullptr, nullptr, L[li][1], pooledB, NV, 1.f);
    gemmK<64, true, 0><<<grid_n(NSOC), B, 0, stream>>>(h_soc, L[li][0], nullptr, nullptr, nullptr, L[li][1], pooledS, NSOC, 1.f);
    gather_max_k<<<grid_w(NC), B, 0, stream>>>(pooledB, rpA, eiA, agg_a, NC);
    gather_max_k<<<grid_w(NC), B, 0, stream>>>(pooledS, rpB, eiB, agg_b, NC);
    // h_con_new = relu(2*(h_con@Ws + b) + (agg_v+agg_s)@Wn)
    gemmK<64, true, 2><<<grid_n(NC), B, 0, stream>>>(cin, L[li][2], agg_a, agg_b, L[li][3], L[li][4], cout, NC, 2.f);
    float* t = cin; cin = cout; cout = t;
  };
  fwd_layer(0);  // l1f
  fwd_layer(2);  // l2f

  // ---- CSR by source (var / soc) ----------------------------------------
  build_csr(vc_src, vc_dst, EVC, NV, rpA, eiA);
  build_csr(sc_src, sc_dst, ESC, NSOC, rpB, eiB);

  // ---- backward half-passes (update var & soc from final h_con) ---------
  float* vin = h_var;  float* vout = h_var2;
  float* sin_ = h_soc; float* sout = h_soc2;
  auto bwd_layer = [&](int li) {
    gemmK<64, true, 0><<<grid_n(NC), B, 0, stream>>>(cin, L[li][0], nullptr, nullptr, nullptr, L[li][1], pooledB, NC, 1.f);
    gather_max_k<<<grid_w(NV), B, 0, stream>>>(pooledB, rpA, eiA, agg_a, NV);
    gather_max_k<<<grid_w(NSOC), B, 0, stream>>>(pooledB, rpB, eiB, agg_b, NSOC);
    gemmK<64, true, 1><<<grid_n(NV), B, 0, stream>>>(vin, L[li][2], agg_a, nullptr, L[li][3], L[li][4], vout, NV, 1.f);
    gemmK<64, true, 1><<<grid_n(NSOC), B, 0, stream>>>(sin_, L[li][2], agg_b, nullptr, L[li][3], L[li][4], sout, NSOC, 1.f);
    float* t = vin; vin = vout; vout = t;
    t = sin_; sin_ = sout; sout = t;
  };
  bwd_layer(1);  // l1b
  bwd_layer(3);  // l2b

  // ---- output MLP (shared Linear applied twice, then head) --------------
  gemmK<64, true, 0><<<grid_n(NV), B, 0, stream>>>(vin, W_hid, nullptr, nullptr, nullptr, b_hid, pooledB, NV, 1.f);
  gemmK<64, true, 0><<<grid_n(NV), B, 0, stream>>>(pooledB, W_hid, nullptr, nullptr, nullptr, b_hid, agg_a, NV, 1.f);
  out_k<<<dim3((unsigned)((NV + 4 * OPW - 1) / (4 * OPW))), B, 0, stream>>>(agg_a, W_out, b_out, (float*)d_out, NV);
}

// Round 3
// 1233.961 us; speedup vs baseline: 2.6398x; 1.4788x over previous
//
#include <hip/hip_runtime.h>

#define NV 100000
#define NC 100000
#define NSOC 20000
#define EVC 2000000
#define ESC 300000
#define H 64

// ---------------------------------------------------------------------------
// LDS-tiled fused GEMM:
//   out[n][j] = act( s1*(dot(X1[n],W1[:,j]) + bias[j]) + [NSEC] dot(X2[n],W2[:,j]) )
// Block = 256 thr = 4 waves; block stages a TR-row X tile in LDS (coalesced),
// then each wave computes TR/4 rows: lane = output col, W col in VGPRs,
// X read as same-address LDS broadcasts (ds_read_b128).
// ---------------------------------------------------------------------------
template<int K1, int NSEC, bool RELU, int TR>
__global__ __launch_bounds__(256) void gemm_lds(
    const float* __restrict__ X1, const float* __restrict__ W1,
    const float* __restrict__ X2, const float* __restrict__ W2,
    const float* __restrict__ bias, float* __restrict__ out,
    int N, float s1)
{
  __shared__ __align__(16) float sx1[TR * K1];
  __shared__ __align__(16) float sx2[NSEC ? TR * H : 4];

  const int n0 = blockIdx.x * TR;

  // ---- stage X1 tile ----
  if constexpr ((K1 & 3) == 0) {
    const float4* X4 = reinterpret_cast<const float4*>(X1);
    float4* S4 = reinterpret_cast<float4*>(sx1);
    const long base4 = (long)n0 * K1 / 4;
    const long lim4 = (long)N * K1 / 4;
    for (int i = threadIdx.x; i < TR * K1 / 4; i += 256)
      S4[i] = (base4 + i < lim4) ? X4[base4 + i] : make_float4(0.f, 0.f, 0.f, 0.f);
  } else {
    const long base = (long)n0 * K1;
    const long lim = (long)N * K1;
    for (int i = threadIdx.x; i < TR * K1; i += 256)
      sx1[i] = (base + i < lim) ? X1[base + i] : 0.f;
  }
  if constexpr (NSEC) {
    const float4* X4 = reinterpret_cast<const float4*>(X2);
    float4* S4 = reinterpret_cast<float4*>(sx2);
    const long base4 = (long)n0 * H / 4;
    const long lim4 = (long)N * H / 4;
    for (int i = threadIdx.x; i < TR * H / 4; i += 256)
      S4[i] = (base4 + i < lim4) ? X4[base4 + i] : make_float4(0.f, 0.f, 0.f, 0.f);
  }
  __syncthreads();

  const int lane = threadIdx.x & 63;
  const int wv = threadIdx.x >> 6;

  float w1[K1];
#pragma unroll
  for (int k = 0; k < K1; ++k) w1[k] = W1[k * H + lane];
  float w2[NSEC ? H : 1];
  if constexpr (NSEC) {
#pragma unroll
    for (int k = 0; k < H; ++k) w2[k] = W2[k * H + lane];
  }
  const float bj = bias[lane];

  constexpr int RPW = TR / 4;
  const int r0 = wv * RPW;

  for (int i = 0; i < RPW; i += 2) {
    const int na = n0 + r0 + i;
    if (na >= N) break;
    const bool wb = (na + 1) < N;

    float accA, accB;
    if constexpr ((K1 & 3) == 0) {
      const float4* xa = reinterpret_cast<const float4*>(sx1 + (r0 + i) * K1);
      const float4* xb = reinterpret_cast<const float4*>(sx1 + (r0 + i + 1) * K1);
      float a0 = 0.f, a1 = 0.f, a2 = 0.f, a3 = 0.f;
      float b0 = 0.f, b1 = 0.f, b2 = 0.f, b3 = 0.f;
#pragma unroll
      for (int k4 = 0; k4 < K1 / 4; ++k4) {
        const float4 va = xa[k4];
        const float4 vb = xb[k4];
        a0 = fmaf(va.x, w1[4 * k4 + 0], a0);
        b0 = fmaf(vb.x, w1[4 * k4 + 0], b0);
        a1 = fmaf(va.y, w1[4 * k4 + 1], a1);
        b1 = fmaf(vb.y, w1[4 * k4 + 1], b1);
        a2 = fmaf(va.z, w1[4 * k4 + 2], a2);
        b2 = fmaf(vb.z, w1[4 * k4 + 2], b2);
        a3 = fmaf(va.w, w1[4 * k4 + 3], a3);
        b3 = fmaf(vb.w, w1[4 * k4 + 3], b3);
      }
      accA = (a0 + a1) + (a2 + a3);
      accB = (b0 + b1) + (b2 + b3);
    } else {
      const float* xa = sx1 + (r0 + i) * K1;
      const float* xb = sx1 + (r0 + i + 1) * K1;
      accA = 0.f; accB = 0.f;
#pragma unroll
      for (int k = 0; k < K1; ++k) {
        accA = fmaf(xa[k], w1[k], accA);
        accB = fmaf(xb[k], w1[k], accB);
      }
    }
    accA = s1 * (accA + bj);
    accB = s1 * (accB + bj);

    if constexpr (NSEC) {
      const float4* xa = reinterpret_cast<const float4*>(sx2 + (r0 + i) * H);
      const float4* xb = reinterpret_cast<const float4*>(sx2 + (r0 + i + 1) * H);
      float a0 = 0.f, a1 = 0.f, a2 = 0.f, a3 = 0.f;
      float b0 = 0.f, b1 = 0.f, b2 = 0.f, b3 = 0.f;
#pragma unroll
      for (int k4 = 0; k4 < H / 4; ++k4) {
        const float4 va = xa[k4];
        const float4 vb = xb[k4];
        a0 = fmaf(va.x, w2[4 * k4 + 0], a0);
        b0 = fmaf(vb.x, w2[4 * k4 + 0], b0);
        a1 = fmaf(va.y, w2[4 * k4 + 1], a1);
        b1 = fmaf(vb.y, w2[4 * k4 + 1], b1);
        a2 = fmaf(va.z, w2[4 * k4 + 2], a2);
        b2 = fmaf(vb.z, w2[4 * k4 + 2], b2);
        a3 = fmaf(va.w, w2[4 * k4 + 3], a3);
        b3 = fmaf(vb.w, w2[4 * k4 + 3], b3);
      }
      accA += (a0 + a1) + (a2 + a3);
      accB += (b0 + b1) + (b2 + b3);
    }

    if constexpr (RELU) { accA = fmaxf(accA, 0.f); accB = fmaxf(accB, 0.f); }
    out[(size_t)na * H + lane] = accA;
    if (wb) out[(size_t)(na + 1) * H + lane] = accB;
  }
}

// ---------------------------------------------------------------------------
// Fused output MLP: z1=relu(x@W+b); z2=relu(z1@W+b); out=z2@Wout+bout.
// Cross-lane hop z1->z2 via per-wave LDS scratch row.
// ---------------------------------------------------------------------------
template<int TR>
__global__ __launch_bounds__(256) void mlp_k(
    const float* __restrict__ X, const float* __restrict__ W,
    const float* __restrict__ bh, const float* __restrict__ Wout,
    const float* __restrict__ bo, float* __restrict__ out, int N)
{
  __shared__ __align__(16) float sx[TR * H];
  __shared__ __align__(16) float sz[4][H];

  const int n0 = blockIdx.x * TR;
  {
    const float4* X4 = reinterpret_cast<const float4*>(X);
    float4* S4 = reinterpret_cast<float4*>(sx);
    const long base4 = (long)n0 * H / 4;
    const long lim4 = (long)N * H / 4;
    for (int i = threadIdx.x; i < TR * H / 4; i += 256)
      S4[i] = (base4 + i < lim4) ? X4[base4 + i] : make_float4(0.f, 0.f, 0.f, 0.f);
  }
  __syncthreads();

  const int lane = threadIdx.x & 63;
  const int wv = threadIdx.x >> 6;
  float w[H];
#pragma unroll
  for (int k = 0; k < H; ++k) w[k] = W[k * H + lane];
  const float bhl = bh[lane];
  const float wo = Wout[lane];
  const float bol = bo[0];

  constexpr int RPW = TR / 4;
  const int r0 = wv * RPW;
  for (int i = 0; i < RPW; ++i) {
    const int n = n0 + r0 + i;
    if (n >= N) break;
    const float4* x4 = reinterpret_cast<const float4*>(sx + (r0 + i) * H);
    float a0 = 0.f, a1 = 0.f, a2 = 0.f, a3 = 0.f;
#pragma unroll
    for (int k4 = 0; k4 < H / 4; ++k4) {
      const float4 v = x4[k4];
      a0 = fmaf(v.x, w[4 * k4 + 0], a0);
      a1 = fmaf(v.y, w[4 * k4 + 1], a1);
      a2 = fmaf(v.z, w[4 * k4 + 2], a2);
      a3 = fmaf(v.w, w[4 * k4 + 3], a3);
    }
    const float z1 = fmaxf((a0 + a1) + (a2 + a3) + bhl, 0.f);
    sz[wv][lane] = z1;
    const float4* z4 = reinterpret_cast<const float4*>(sz[wv]);
    a0 = 0.f; a1 = 0.f; a2 = 0.f; a3 = 0.f;
#pragma unroll
    for (int k4 = 0; k4 < H / 4; ++k4) {
      const float4 v = z4[k4];
      a0 = fmaf(v.x, w[4 * k4 + 0], a0);
      a1 = fmaf(v.y, w[4 * k4 + 1], a1);
      a2 = fmaf(v.z, w[4 * k4 + 2], a2);
      a3 = fmaf(v.w, w[4 * k4 + 3], a3);
    }
    const float z2 = fmaxf((a0 + a1) + (a2 + a3) + bhl, 0.f);
    float v = z2 * wo;
#pragma unroll
    for (int off = 32; off; off >>= 1) v += __shfl_down(v, off);
    if (lane == 0) out[n] = v + bol;
  }
}

// ---------------------------------------------------------------------------
// CSR build: histogram -> 2-level exclusive scan -> fill
// ---------------------------------------------------------------------------
__global__ __launch_bounds__(256) void hist_k(const int* __restrict__ key,
                                              int* __restrict__ deg, int E) {
  int i = blockIdx.x * 256 + threadIdx.x;
  if (i < E) atomicAdd(&deg[key[i]], 1);
}

__global__ __launch_bounds__(256) void scan1_k(const int* __restrict__ deg,
                                               int* __restrict__ bsum, int N) {
  __shared__ int s[256];
  const int t = threadIdx.x;
  const int gi = blockIdx.x * 256 + t;
  s[t] = (gi < N) ? deg[gi] : 0;
  __syncthreads();
  for (int off = 128; off; off >>= 1) {
    if (t < off) s[t] += s[t + off];
    __syncthreads();
  }
  if (t == 0) bsum[blockIdx.x] = s[0];
}

__global__ __launch_bounds__(512) void scan2_k(const int* __restrict__ bsum,
                                               int* __restrict__ bofs, int NB) {
  __shared__ int s[512];
  const int t = threadIdx.x;
  const int v = (t < NB) ? bsum[t] : 0;
  s[t] = v;
  __syncthreads();
  for (int off = 1; off < 512; off <<= 1) {
    int x = (t >= off) ? s[t - off] : 0;
    __syncthreads();
    s[t] += x;
    __syncthreads();
  }
  if (t < NB) bofs[t] = s[t] - v;  // exclusive
}

__global__ __launch_bounds__(256) void scan3_k(const int* __restrict__ deg,
                                               const int* __restrict__ bofs,
                                               int* __restrict__ rp, int N) {
  __shared__ int s[256];
  const int t = threadIdx.x;
  const int gi = blockIdx.x * 256 + t;
  const int v = (gi < N) ? deg[gi] : 0;
  s[t] = v;
  __syncthreads();
  for (int off = 1; off < 256; off <<= 1) {
    int x = (t >= off) ? s[t - off] : 0;
    __syncthreads();
    s[t] += x;
    __syncthreads();
  }
  const int incl = s[t];
  const int base = bofs[blockIdx.x];
  if (gi < N) rp[gi] = base + incl - v;
  if (gi == N - 1) rp[N] = base + incl;
}

__global__ __launch_bounds__(256) void fill_k(const int* __restrict__ key,
                                              const int* __restrict__ payload,
                                              const int* __restrict__ rp,
                                              int* __restrict__ cur,
                                              int* __restrict__ ei, int E) {
  int i = blockIdx.x * 256 + threadIdx.x;
  if (i < E) {
    const int d = key[i];
    const int p = atomicAdd(&cur[d], 1);
    ei[rp[d] + p] = payload[i];
  }
}

// ---------------------------------------------------------------------------
// CSR gather segment-max (4x unrolled: independent edge-id + row loads).
// ---------------------------------------------------------------------------
__device__ __forceinline__ float gmax_csr(const float* __restrict__ pooled,
                                          const int* __restrict__ rp,
                                          const int* __restrict__ ei,
                                          int n, int lane) {
  const int p0 = rp[n], p1 = rp[n + 1];
  float m0 = 0.f, m1 = 0.f, m2 = 0.f, m3 = 0.f;
  int p = p0;
  for (; p + 4 <= p1; p += 4) {
    const int s0 = ei[p + 0], s1 = ei[p + 1];
    const int s2 = ei[p + 2], s3 = ei[p + 3];
    m0 = fmaxf(m0, pooled[(size_t)s0 * H + lane]);
    m1 = fmaxf(m1, pooled[(size_t)s1 * H + lane]);
    m2 = fmaxf(m2, pooled[(size_t)s2 * H + lane]);
    m3 = fmaxf(m3, pooled[(size_t)s3 * H + lane]);
  }
  for (; p < p1; ++p) m0 = fmaxf(m0, pooled[(size_t)ei[p] * H + lane]);
  return fmaxf(fmaxf(m0, m1), fmaxf(m2, m3));
}

__global__ __launch_bounds__(256) void gather_max_k(
    const float* __restrict__ pooled, const int* __restrict__ rp,
    const int* __restrict__ ei, float* __restrict__ out, int N)
{
  const int lane = threadIdx.x & 63;
  const int n = __builtin_amdgcn_readfirstlane(blockIdx.x * 4 + (threadIdx.x >> 6));
  if (n >= N) return;
  out[(size_t)n * H + lane] = gmax_csr(pooled, rp, ei, n, lane);
}

// Fused: out[n] = gmax_A(pooledA) + gmax_B(pooledB)  (forward con-aggregation)
__global__ __launch_bounds__(256) void gather2_k(
    const float* __restrict__ pooledA, const int* __restrict__ rpA,
    const int* __restrict__ eiA,
    const float* __restrict__ pooledB, const int* __restrict__ rpB,
    const int* __restrict__ eiB,
    float* __restrict__ out, int N)
{
  const int lane = threadIdx.x & 63;
  const int n = __builtin_amdgcn_readfirstlane(blockIdx.x * 4 + (threadIdx.x >> 6));
  if (n >= N) return;
  const float a = gmax_csr(pooledA, rpA, eiA, n, lane);
  const float b = gmax_csr(pooledB, rpB, eiB, n, lane);
  out[(size_t)n * H + lane] = a + b;
}

extern "C" void kernel_launch(void* const* d_in, const int* in_sizes, int n_in,
                              void* d_out, int out_size, void* d_ws, size_t ws_size,
                              hipStream_t stream) {
  const float* var_x = (const float*)d_in[0];
  const float* con_x = (const float*)d_in[1];
  const float* soc_x = (const float*)d_in[2];
  const float* W_var = (const float*)d_in[3];
  const float* b_var = (const float*)d_in[4];
  const float* W_con = (const float*)d_in[5];
  const float* b_con = (const float*)d_in[6];
  const float* W_soc = (const float*)d_in[7];
  const float* b_soc = (const float*)d_in[8];
  const float* L[4][5];  // L[0]=l1f, L[1]=l1b, L[2]=l2f, L[3]=l2b
  for (int l = 0; l < 4; ++l)
    for (int p = 0; p < 5; ++p)
      L[l][p] = (const float*)d_in[9 + l * 5 + p];
  const float* W_hid = (const float*)d_in[29];
  const float* b_hid = (const float*)d_in[30];
  const float* W_out = (const float*)d_in[31];
  const float* b_out = (const float*)d_in[32];
  const int* vc_src = (const int*)d_in[33];
  const int* vc_dst = (const int*)d_in[34];
  const int* sc_src = (const int*)d_in[35];
  const int* sc_dst = (const int*)d_in[36];

  const size_t BIG = (size_t)NV * H * sizeof(float);   // 25.6 MB
  const size_t SOC = (size_t)NSOC * H * sizeof(float); // 5.12 MB
  const size_t RPB = ((size_t)(NV + 2) * 4 + 255) & ~255ull;
  char* ws = (char*)d_ws;
  float* h_var   = (float*)(ws + 0 * BIG);
  float* h_var2  = (float*)(ws + 1 * BIG);
  float* h_con   = (float*)(ws + 2 * BIG);
  float* h_con2  = (float*)(ws + 3 * BIG);
  float* pooledB = (float*)(ws + 4 * BIG);
  float* agg_a   = (float*)(ws + 5 * BIG);
  float* agg_b   = (float*)(ws + 6 * BIG);
  float* h_soc   = (float*)(ws + 7 * BIG);
  float* h_soc2  = (float*)(ws + 7 * BIG + SOC);
  float* pooledS = (float*)(ws + 7 * BIG + 2 * SOC);
  char* csr = ws + 7 * BIG + 3 * SOC;
  int* rpA  = (int*)(csr);
  int* eiA  = (int*)(csr + RPB);
  int* rpB  = (int*)(csr + RPB + (size_t)EVC * 4);
  int* eiB  = (int*)(csr + 2 * RPB + (size_t)EVC * 4);
  char* aux = csr + 2 * RPB + (size_t)(EVC + ESC) * 4;
  int* deg  = (int*)(aux);
  int* cur  = (int*)(aux + RPB);
  int* bsum = (int*)(aux + 2 * RPB);
  int* bofs = (int*)(aux + 2 * RPB + 4096);

  constexpr int TR = 64;
  auto grid_l = [](int n) { return dim3((unsigned)((n + TR - 1) / TR)); };
  auto grid_t = [](int n) { return dim3((unsigned)((n + 255) / 256)); };
  auto grid_w = [](int n) { return dim3((unsigned)((n + 3) / 4)); };
  const dim3 B(256);

  auto build_csr = [&](const int* key, const int* payload, int E, int Nn,
                       int* rp, int* ei) {
    const int nb = (Nn + 255) / 256;
    hipMemsetAsync(deg, 0, (size_t)Nn * 4, stream);
    hist_k<<<grid_t(E), B, 0, stream>>>(key, deg, E);
    scan1_k<<<dim3((unsigned)nb), B, 0, stream>>>(deg, bsum, Nn);
    scan2_k<<<dim3(1), dim3(512), 0, stream>>>(bsum, bofs, nb);
    scan3_k<<<dim3((unsigned)nb), B, 0, stream>>>(deg, bofs, rp, Nn);
    hipMemsetAsync(cur, 0, (size_t)Nn * 4, stream);
    fill_k<<<grid_t(E), B, 0, stream>>>(key, payload, rp, cur, ei, E);
  };

  // ---- embeddings -------------------------------------------------------
  gemm_lds<7, 0, true, TR><<<grid_l(NV), B, 0, stream>>>(var_x, W_var, nullptr, nullptr, b_var, h_var, NV, 1.f);
  gemm_lds<4, 0, true, TR><<<grid_l(NC), B, 0, stream>>>(con_x, W_con, nullptr, nullptr, b_con, h_con, NC, 1.f);
  gemm_lds<6, 0, true, TR><<<grid_l(NSOC), B, 0, stream>>>(soc_x, W_soc, nullptr, nullptr, b_soc, h_soc, NSOC, 1.f);

  // ---- CSR by destination (constraints) ---------------------------------
  build_csr(vc_dst, vc_src, EVC, NC, rpA, eiA);
  build_csr(sc_dst, sc_src, ESC, NC, rpB, eiB);

  // ---- forward half-passes (update constraints) -------------------------
  float* cin = h_con;
  float* cout = h_con2;
  auto fwd_layer = [&](int li) {
    gemm_lds<64, 0, true, TR><<<grid_l(NV), B, 0, stream>>>(h_var, L[li][0], nullptr, nullptr, L[li][1], pooledB, NV, 1.f);
    gemm_lds<64, 0, true, TR><<<grid_l(NSOC), B, 0, stream>>>(h_soc, L[li][0], nullptr, nullptr, L[li][1], pooledS, NSOC, 1.f);
    gather2_k<<<grid_w(NC), B, 0, stream>>>(pooledB, rpA, eiA, pooledS, rpB, eiB, agg_a, NC);
    // h_con_new = relu(2*(h_con@Ws + b) + agg@Wn)
    gemm_lds<64, 1, true, TR><<<grid_l(NC), B, 0, stream>>>(cin, L[li][2], agg_a, L[li][3], L[li][4], cout, NC, 2.f);
    float* t = cin; cin = cout; cout = t;
  };
  fwd_layer(0);  // l1f
  fwd_layer(2);  // l2f

  // ---- CSR by source (var / soc) ----------------------------------------
  build_csr(vc_src, vc_dst, EVC, NV, rpA, eiA);
  build_csr(sc_src, sc_dst, ESC, NSOC, rpB, eiB);

  // ---- backward half-passes (update var & soc from final h_con) ---------
  float* vin = h_var;  float* vout = h_var2;
  float* sin_ = h_soc; float* sout = h_soc2;
  auto bwd_layer = [&](int li) {
    gemm_lds<64, 0, true, TR><<<grid_l(NC), B, 0, stream>>>(cin, L[li][0], nullptr, nullptr, L[li][1], pooledB, NC, 1.f);
    gather_max_k<<<grid_w(NV), B, 0, stream>>>(pooledB, rpA, eiA, agg_a, NV);
    gather_max_k<<<grid_w(NSOC), B, 0, stream>>>(pooledB, rpB, eiB, agg_b, NSOC);
    gemm_lds<64, 1, true, TR><<<grid_l(NV), B, 0, stream>>>(vin, L[li][2], agg_a, L[li][3], L[li][4], vout, NV, 1.f);
    gemm_lds<64, 1, true, TR><<<grid_l(NSOC), B, 0, stream>>>(sin_, L[li][2], agg_b, L[li][3], L[li][4], sout, NSOC, 1.f);
    float* t = vin; vin = vout; vout = t;
    t = sin_; sin_ = sout; sout = t;
  };
  bwd_layer(1);  // l1b
  bwd_layer(3);  // l2b

  // ---- fused output MLP -------------------------------------------------
  mlp_k<TR><<<grid_l(NV), B, 0, stream>>>(vin, W_hid, b_hid, W_out, b_out, (float*)d_out, NV);
}

// Round 4
// 1113.782 us; speedup vs baseline: 2.9247x; 1.1079x over previous
//
#include <hip/hip_runtime.h>

#define NV 100000
#define NC 100000
#define NSOC 20000
#define EVC 2000000
#define ESC 300000
#define H 64

constexpr int BSH = 7;       // 128 nodes per bucket
constexpr int NBMAX = 1024;  // max buckets (ceil(100000/128) = 782)
constexpr int EPB = 8192;    // edges per block in bucket passes

// ---------------------------------------------------------------------------
// LDS-tiled fused GEMM:
//   out[n][j] = act( s1*(dot(X1[n],W1[:,j]) + bias[j]) + [NSEC] dot(X2[n],W2[:,j]) )
// ---------------------------------------------------------------------------
template<int K1, int NSEC, bool RELU, int TR>
__global__ __launch_bounds__(256) void gemm_lds(
    const float* __restrict__ X1, const float* __restrict__ W1,
    const float* __restrict__ X2, const float* __restrict__ W2,
    const float* __restrict__ bias, float* __restrict__ out,
    int N, float s1)
{
  __shared__ __align__(16) float sx1[TR * K1];
  __shared__ __align__(16) float sx2[NSEC ? TR * H : 4];

  const int n0 = blockIdx.x * TR;

  if constexpr ((K1 & 3) == 0) {
    const float4* X4 = reinterpret_cast<const float4*>(X1);
    float4* S4 = reinterpret_cast<float4*>(sx1);
    const long base4 = (long)n0 * K1 / 4;
    const long lim4 = (long)N * K1 / 4;
    for (int i = threadIdx.x; i < TR * K1 / 4; i += 256)
      S4[i] = (base4 + i < lim4) ? X4[base4 + i] : make_float4(0.f, 0.f, 0.f, 0.f);
  } else {
    const long base = (long)n0 * K1;
    const long lim = (long)N * K1;
    for (int i = threadIdx.x; i < TR * K1; i += 256)
      sx1[i] = (base + i < lim) ? X1[base + i] : 0.f;
  }
  if constexpr (NSEC) {
    const float4* X4 = reinterpret_cast<const float4*>(X2);
    float4* S4 = reinterpret_cast<float4*>(sx2);
    const long base4 = (long)n0 * H / 4;
    const long lim4 = (long)N * H / 4;
    for (int i = threadIdx.x; i < TR * H / 4; i += 256)
      S4[i] = (base4 + i < lim4) ? X4[base4 + i] : make_float4(0.f, 0.f, 0.f, 0.f);
  }
  __syncthreads();

  const int lane = threadIdx.x & 63;
  const int wv = threadIdx.x >> 6;

  float w1[K1];
#pragma unroll
  for (int k = 0; k < K1; ++k) w1[k] = W1[k * H + lane];
  float w2[NSEC ? H : 1];
  if constexpr (NSEC) {
#pragma unroll
    for (int k = 0; k < H; ++k) w2[k] = W2[k * H + lane];
  }
  const float bj = bias[lane];

  constexpr int RPW = TR / 4;
  const int r0 = wv * RPW;

  for (int i = 0; i < RPW; i += 2) {
    const int na = n0 + r0 + i;
    if (na >= N) break;
    const bool wb = (na + 1) < N;

    float accA, accB;
    if constexpr ((K1 & 3) == 0) {
      const float4* xa = reinterpret_cast<const float4*>(sx1 + (r0 + i) * K1);
      const float4* xb = reinterpret_cast<const float4*>(sx1 + (r0 + i + 1) * K1);
      float a0 = 0.f, a1 = 0.f, a2 = 0.f, a3 = 0.f;
      float b0 = 0.f, b1 = 0.f, b2 = 0.f, b3 = 0.f;
#pragma unroll
      for (int k4 = 0; k4 < K1 / 4; ++k4) {
        const float4 va = xa[k4];
        const float4 vb = xb[k4];
        a0 = fmaf(va.x, w1[4 * k4 + 0], a0);
        b0 = fmaf(vb.x, w1[4 * k4 + 0], b0);
        a1 = fmaf(va.y, w1[4 * k4 + 1], a1);
        b1 = fmaf(vb.y, w1[4 * k4 + 1], b1);
        a2 = fmaf(va.z, w1[4 * k4 + 2], a2);
        b2 = fmaf(vb.z, w1[4 * k4 + 2], b2);
        a3 = fmaf(va.w, w1[4 * k4 + 3], a3);
        b3 = fmaf(vb.w, w1[4 * k4 + 3], b3);
      }
      accA = (a0 + a1) + (a2 + a3);
      accB = (b0 + b1) + (b2 + b3);
    } else {
      const float* xa = sx1 + (r0 + i) * K1;
      const float* xb = sx1 + (r0 + i + 1) * K1;
      accA = 0.f; accB = 0.f;
#pragma unroll
      for (int k = 0; k < K1; ++k) {
        accA = fmaf(xa[k], w1[k], accA);
        accB = fmaf(xb[k], w1[k], accB);
      }
    }
    accA = s1 * (accA + bj);
    accB = s1 * (accB + bj);

    if constexpr (NSEC) {
      const float4* xa = reinterpret_cast<const float4*>(sx2 + (r0 + i) * H);
      const float4* xb = reinterpret_cast<const float4*>(sx2 + (r0 + i + 1) * H);
      float a0 = 0.f, a1 = 0.f, a2 = 0.f, a3 = 0.f;
      float b0 = 0.f, b1 = 0.f, b2 = 0.f, b3 = 0.f;
#pragma unroll
      for (int k4 = 0; k4 < H / 4; ++k4) {
        const float4 va = xa[k4];
        const float4 vb = xb[k4];
        a0 = fmaf(va.x, w2[4 * k4 + 0], a0);
        b0 = fmaf(vb.x, w2[4 * k4 + 0], b0);
        a1 = fmaf(va.y, w2[4 * k4 + 1], a1);
        b1 = fmaf(vb.y, w2[4 * k4 + 1], b1);
        a2 = fmaf(va.z, w2[4 * k4 + 2], a2);
        b2 = fmaf(vb.z, w2[4 * k4 + 2], b2);
        a3 = fmaf(va.w, w2[4 * k4 + 3], a3);
        b3 = fmaf(vb.w, w2[4 * k4 + 3], b3);
      }
      accA += (a0 + a1) + (a2 + a3);
      accB += (b0 + b1) + (b2 + b3);
    }

    if constexpr (RELU) { accA = fmaxf(accA, 0.f); accB = fmaxf(accB, 0.f); }
    out[(size_t)na * H + lane] = accA;
    if (wb) out[(size_t)(na + 1) * H + lane] = accB;
  }
}

// ---------------------------------------------------------------------------
// Fused output MLP: z1=relu(x@W+b); z2=relu(z1@W+b); out=z2@Wout+bout.
// ---------------------------------------------------------------------------
template<int TR>
__global__ __launch_bounds__(256) void mlp_k(
    const float* __restrict__ X, const float* __restrict__ W,
    const float* __restrict__ bh, const float* __restrict__ Wout,
    const float* __restrict__ bo, float* __restrict__ out, int N)
{
  __shared__ __align__(16) float sx[TR * H];
  __shared__ __align__(16) float sz[4][H];

  const int n0 = blockIdx.x * TR;
  {
    const float4* X4 = reinterpret_cast<const float4*>(X);
    float4* S4 = reinterpret_cast<float4*>(sx);
    const long base4 = (long)n0 * H / 4;
    const long lim4 = (long)N * H / 4;
    for (int i = threadIdx.x; i < TR * H / 4; i += 256)
      S4[i] = (base4 + i < lim4) ? X4[base4 + i] : make_float4(0.f, 0.f, 0.f, 0.f);
  }
  __syncthreads();

  const int lane = threadIdx.x & 63;
  const int wv = threadIdx.x >> 6;
  float w[H];
#pragma unroll
  for (int k = 0; k < H; ++k) w[k] = W[k * H + lane];
  const float bhl = bh[lane];
  const float wo = Wout[lane];
  const float bol = bo[0];

  constexpr int RPW = TR / 4;
  const int r0 = wv * RPW;
  for (int i = 0; i < RPW; ++i) {
    const int n = n0 + r0 + i;
    if (n >= N) break;
    const float4* x4 = reinterpret_cast<const float4*>(sx + (r0 + i) * H);
    float a0 = 0.f, a1 = 0.f, a2 = 0.f, a3 = 0.f;
#pragma unroll
    for (int k4 = 0; k4 < H / 4; ++k4) {
      const float4 v = x4[k4];
      a0 = fmaf(v.x, w[4 * k4 + 0], a0);
      a1 = fmaf(v.y, w[4 * k4 + 1], a1);
      a2 = fmaf(v.z, w[4 * k4 + 2], a2);
      a3 = fmaf(v.w, w[4 * k4 + 3], a3);
    }
    const float z1 = fmaxf((a0 + a1) + (a2 + a3) + bhl, 0.f);
    sz[wv][lane] = z1;
    const float4* z4 = reinterpret_cast<const float4*>(sz[wv]);
    a0 = 0.f; a1 = 0.f; a2 = 0.f; a3 = 0.f;
#pragma unroll
    for (int k4 = 0; k4 < H / 4; ++k4) {
      const float4 v = z4[k4];
      a0 = fmaf(v.x, w[4 * k4 + 0], a0);
      a1 = fmaf(v.y, w[4 * k4 + 1], a1);
      a2 = fmaf(v.z, w[4 * k4 + 2], a2);
      a3 = fmaf(v.w, w[4 * k4 + 3], a3);
    }
    const float z2 = fmaxf((a0 + a1) + (a2 + a3) + bhl, 0.f);
    float v = z2 * wo;
#pragma unroll
    for (int off = 32; off; off >>= 1) v += __shfl_down(v, off);
    if (lane == 0) out[n] = v + bol;
  }
}

// ---------------------------------------------------------------------------
// Bucketed CSR build.
// Stage 1: bucket histogram (LDS pre-aggregated).
// ---------------------------------------------------------------------------
__global__ __launch_bounds__(256) void bhist_k(const int* __restrict__ key,
                                               int* __restrict__ bcnt, int E, int nb) {
  __shared__ int h[NBMAX];
  for (int i = threadIdx.x; i < nb; i += 256) h[i] = 0;
  __syncthreads();
  const int base = blockIdx.x * EPB;
  for (int i = threadIdx.x; i < EPB; i += 256) {
    const int e = base + i;
    if (e < E) atomicAdd(&h[key[e] >> BSH], 1);
  }
  __syncthreads();
  for (int i = threadIdx.x; i < nb; i += 256)
    if (h[i]) atomicAdd(&bcnt[i], h[i]);
}

// Stage 2: single-block exclusive scan over bucket counts -> bbase, bcur.
__global__ __launch_bounds__(1024) void bscan_k(const int* __restrict__ bcnt,
                                                int* __restrict__ bcur, int nb) {
  __shared__ int s[1024];
  const int t = threadIdx.x;
  const int v = (t < nb) ? bcnt[t] : 0;
  s[t] = v;
  __syncthreads();
  for (int off = 1; off < 1024; off <<= 1) {
    int x = (t >= off) ? s[t - off] : 0;
    __syncthreads();
    s[t] += x;
    __syncthreads();
  }
  if (t < nb) bcur[t] = s[t] - v;  // exclusive
}

// Stage 3: scatter (key,payload) into bucket-sorted order.
__global__ __launch_bounds__(256) void bscatter_k(
    const int* __restrict__ key, const int* __restrict__ payload,
    int* __restrict__ bcur, int2* __restrict__ sorted, int E, int nb) {
  __shared__ int h[NBMAX];
  __shared__ int gb[NBMAX];
  __shared__ unsigned short lr[EPB];
  for (int i = threadIdx.x; i < nb; i += 256) h[i] = 0;
  __syncthreads();
  const int base = blockIdx.x * EPB;
  for (int i = threadIdx.x; i < EPB; i += 256) {
    const int e = base + i;
    if (e < E) lr[i] = (unsigned short)atomicAdd(&h[key[e] >> BSH], 1);
  }
  __syncthreads();
  for (int i = threadIdx.x; i < nb; i += 256)
    if (h[i]) gb[i] = atomicAdd(&bcur[i], h[i]);
  __syncthreads();
  for (int i = threadIdx.x; i < EPB; i += 256) {
    const int e = base + i;
    if (e < E) {
      const int k = key[e];
      sorted[gb[k >> BSH] + lr[i]] = make_int2(k, payload[e]);
    }
  }
}

// Stage 4: per-node degree histogram over bucket-sorted keys (L2-local).
__global__ __launch_bounds__(256) void hist_sorted_k(const int2* __restrict__ sorted,
                                                     int* __restrict__ deg, int E) {
  const int i = blockIdx.x * 256 + threadIdx.x;
  if (i < E) atomicAdd(&deg[sorted[i].x], 1);
}

// Stage 5: fill CSR payloads from bucket-sorted edges (L2-local windows).
__global__ __launch_bounds__(256) void fill_sorted_k(
    const int2* __restrict__ sorted, const int* __restrict__ rp,
    int* __restrict__ cur, int* __restrict__ ei, int E) {
  const int i = blockIdx.x * 256 + threadIdx.x;
  if (i < E) {
    const int2 kp = sorted[i];
    const int p = atomicAdd(&cur[kp.x], 1);
    ei[rp[kp.x] + p] = kp.y;
  }
}

// ---------------------------------------------------------------------------
// Node-count exclusive scan (3 kernels) -> rowptr
// ---------------------------------------------------------------------------
__global__ __launch_bounds__(256) void scan1_k(const int* __restrict__ deg,
                                               int* __restrict__ bsum, int N) {
  __shared__ int s[256];
  const int t = threadIdx.x;
  const int gi = blockIdx.x * 256 + t;
  s[t] = (gi < N) ? deg[gi] : 0;
  __syncthreads();
  for (int off = 128; off; off >>= 1) {
    if (t < off) s[t] += s[t + off];
    __syncthreads();
  }
  if (t == 0) bsum[blockIdx.x] = s[0];
}

__global__ __launch_bounds__(512) void scan2_k(const int* __restrict__ bsum,
                                               int* __restrict__ bofs, int NB) {
  __shared__ int s[512];
  const int t = threadIdx.x;
  const int v = (t < NB) ? bsum[t] : 0;
  s[t] = v;
  __syncthreads();
  for (int off = 1; off < 512; off <<= 1) {
    int x = (t >= off) ? s[t - off] : 0;
    __syncthreads();
    s[t] += x;
    __syncthreads();
  }
  if (t < NB) bofs[t] = s[t] - v;  // exclusive
}

__global__ __launch_bounds__(256) void scan3_k(const int* __restrict__ deg,
                                               const int* __restrict__ bofs,
                                               int* __restrict__ rp, int N) {
  __shared__ int s[256];
  const int t = threadIdx.x;
  const int gi = blockIdx.x * 256 + t;
  const int v = (gi < N) ? deg[gi] : 0;
  s[t] = v;
  __syncthreads();
  for (int off = 1; off < 256; off <<= 1) {
    int x = (t >= off) ? s[t - off] : 0;
    __syncthreads();
    s[t] += x;
    __syncthreads();
  }
  const int incl = s[t];
  const int base = bofs[blockIdx.x];
  if (gi < N) rp[gi] = base + incl - v;
  if (gi == N - 1) rp[N] = base + incl;
}

// ---------------------------------------------------------------------------
// CSR gather segment-max (4x unrolled).
// ---------------------------------------------------------------------------
__device__ __forceinline__ float gmax_csr(const float* __restrict__ pooled,
                                          const int* __restrict__ rp,
                                          const int* __restrict__ ei,
                                          int n, int lane) {
  const int p0 = rp[n], p1 = rp[n + 1];
  float m0 = 0.f, m1 = 0.f, m2 = 0.f, m3 = 0.f;
  int p = p0;
  for (; p + 4 <= p1; p += 4) {
    const int s0 = ei[p + 0], s1 = ei[p + 1];
    const int s2 = ei[p + 2], s3 = ei[p + 3];
    m0 = fmaxf(m0, pooled[(size_t)s0 * H + lane]);
    m1 = fmaxf(m1, pooled[(size_t)s1 * H + lane]);
    m2 = fmaxf(m2, pooled[(size_t)s2 * H + lane]);
    m3 = fmaxf(m3, pooled[(size_t)s3 * H + lane]);
  }
  for (; p < p1; ++p) m0 = fmaxf(m0, pooled[(size_t)ei[p] * H + lane]);
  return fmaxf(fmaxf(m0, m1), fmaxf(m2, m3));
}

__global__ __launch_bounds__(256) void gather_max_k(
    const float* __restrict__ pooled, const int* __restrict__ rp,
    const int* __restrict__ ei, float* __restrict__ out, int N)
{
  const int lane = threadIdx.x & 63;
  const int n = __builtin_amdgcn_readfirstlane(blockIdx.x * 4 + (threadIdx.x >> 6));
  if (n >= N) return;
  out[(size_t)n * H + lane] = gmax_csr(pooled, rp, ei, n, lane);
}

__global__ __launch_bounds__(256) void gather2_k(
    const float* __restrict__ pooledA, const int* __restrict__ rpA,
    const int* __restrict__ eiA,
    const float* __restrict__ pooledB, const int* __restrict__ rpB,
    const int* __restrict__ eiB,
    float* __restrict__ out, int N)
{
  const int lane = threadIdx.x & 63;
  const int n = __builtin_amdgcn_readfirstlane(blockIdx.x * 4 + (threadIdx.x >> 6));
  if (n >= N) return;
  const float a = gmax_csr(pooledA, rpA, eiA, n, lane);
  const float b = gmax_csr(pooledB, rpB, eiB, n, lane);
  out[(size_t)n * H + lane] = a + b;
}

extern "C" void kernel_launch(void* const* d_in, const int* in_sizes, int n_in,
                              void* d_out, int out_size, void* d_ws, size_t ws_size,
                              hipStream_t stream) {
  const float* var_x = (const float*)d_in[0];
  const float* con_x = (const float*)d_in[1];
  const float* soc_x = (const float*)d_in[2];
  const float* W_var = (const float*)d_in[3];
  const float* b_var = (const float*)d_in[4];
  const float* W_con = (const float*)d_in[5];
  const float* b_con = (const float*)d_in[6];
  const float* W_soc = (const float*)d_in[7];
  const float* b_soc = (const float*)d_in[8];
  const float* L[4][5];  // L[0]=l1f, L[1]=l1b, L[2]=l2f, L[3]=l2b
  for (int l = 0; l < 4; ++l)
    for (int p = 0; p < 5; ++p)
      L[l][p] = (const float*)d_in[9 + l * 5 + p];
  const float* W_hid = (const float*)d_in[29];
  const float* b_hid = (const float*)d_in[30];
  const float* W_out = (const float*)d_in[31];
  const float* b_out = (const float*)d_in[32];
  const int* vc_src = (const int*)d_in[33];
  const int* vc_dst = (const int*)d_in[34];
  const int* sc_src = (const int*)d_in[35];
  const int* sc_dst = (const int*)d_in[36];

  const size_t BIG = (size_t)NV * H * sizeof(float);   // 25.6 MB
  const size_t SOC = (size_t)NSOC * H * sizeof(float); // 5.12 MB
  const size_t RPB = ((size_t)(NV + 2) * 4 + 255) & ~255ull;
  char* ws = (char*)d_ws;
  float* h_var   = (float*)(ws + 0 * BIG);
  float* h_var2  = (float*)(ws + 1 * BIG);
  float* h_con   = (float*)(ws + 2 * BIG);
  float* h_con2  = (float*)(ws + 3 * BIG);
  float* pooledB = (float*)(ws + 4 * BIG);
  float* agg_a   = (float*)(ws + 5 * BIG);
  float* agg_b   = (float*)(ws + 6 * BIG);     // also hosts `sorted` during builds
  int2*  sorted  = (int2*)(ws + 6 * BIG);      // 16 MB < BIG; dead during builds
  float* h_soc   = (float*)(ws + 7 * BIG);
  float* h_soc2  = (float*)(ws + 7 * BIG + SOC);
  float* pooledS = (float*)(ws + 7 * BIG + 2 * SOC);
  char* csr = ws + 7 * BIG + 3 * SOC;
  int* rpA  = (int*)(csr);
  int* eiA  = (int*)(csr + RPB);
  int* rpB  = (int*)(csr + RPB + (size_t)EVC * 4);
  int* eiB  = (int*)(csr + 2 * RPB + (size_t)EVC * 4);
  char* aux = csr + 2 * RPB + (size_t)(EVC + ESC) * 4;
  int* deg  = (int*)(aux);
  int* cur  = (int*)(aux + RPB);
  int* bsum = (int*)(aux + 2 * RPB);
  int* bofs = (int*)(aux + 2 * RPB + 4096);
  int* bcnt = (int*)(aux + 2 * RPB + 8192);
  int* bcur = (int*)(aux + 2 * RPB + 12288);

  constexpr int TR = 64;
  auto grid_l = [](int n) { return dim3((unsigned)((n + TR - 1) / TR)); };
  auto grid_t = [](int n) { return dim3((unsigned)((n + 255) / 256)); };
  auto grid_w = [](int n) { return dim3((unsigned)((n + 3) / 4)); };
  auto grid_b = [](int e) { return dim3((unsigned)((e + EPB - 1) / EPB)); };
  const dim3 B(256);

  auto build_csr = [&](const int* key, const int* payload, int E, int Nn,
                       int* rp, int* ei) {
    const int nb = (Nn + (1 << BSH) - 1) >> BSH;   // buckets
    const int ns = (Nn + 255) / 256;               // node-scan blocks
    // bucket sort
    hipMemsetAsync(bcnt, 0, (size_t)nb * 4, stream);
    bhist_k<<<grid_b(E), B, 0, stream>>>(key, bcnt, E, nb);
    bscan_k<<<dim3(1), dim3(1024), 0, stream>>>(bcnt, bcur, nb);
    bscatter_k<<<grid_b(E), B, 0, stream>>>(key, payload, bcur, sorted, E, nb);
    // node degrees + rowptr
    hipMemsetAsync(deg, 0, (size_t)Nn * 4, stream);
    hist_sorted_k<<<grid_t(E), B, 0, stream>>>(sorted, deg, E);
    scan1_k<<<dim3((unsigned)ns), B, 0, stream>>>(deg, bsum, Nn);
    scan2_k<<<dim3(1), dim3(512), 0, stream>>>(bsum, bofs, ns);
    scan3_k<<<dim3((unsigned)ns), B, 0, stream>>>(deg, bofs, rp, Nn);
    // fill payloads
    hipMemsetAsync(cur, 0, (size_t)Nn * 4, stream);
    fill_sorted_k<<<grid_t(E), B, 0, stream>>>(sorted, rp, cur, ei, E);
  };

  // ---- embeddings -------------------------------------------------------
  gemm_lds<7, 0, true, TR><<<grid_l(NV), B, 0, stream>>>(var_x, W_var, nullptr, nullptr, b_var, h_var, NV, 1.f);
  gemm_lds<4, 0, true, TR><<<grid_l(NC), B, 0, stream>>>(con_x, W_con, nullptr, nullptr, b_con, h_con, NC, 1.f);
  gemm_lds<6, 0, true, TR><<<grid_l(NSOC), B, 0, stream>>>(soc_x, W_soc, nullptr, nullptr, b_soc, h_soc, NSOC, 1.f);

  // ---- CSR by destination (constraints) ---------------------------------
  build_csr(vc_dst, vc_src, EVC, NC, rpA, eiA);
  build_csr(sc_dst, sc_src, ESC, NC, rpB, eiB);

  // ---- forward half-passes (update constraints) -------------------------
  float* cin = h_con;
  float* cout = h_con2;
  auto fwd_layer = [&](int li) {
    gemm_lds<64, 0, true, TR><<<grid_l(NV), B, 0, stream>>>(h_var, L[li][0], nullptr, nullptr, L[li][1], pooledB, NV, 1.f);
    gemm_lds<64, 0, true, TR><<<grid_l(NSOC), B, 0, stream>>>(h_soc, L[li][0], nullptr, nullptr, L[li][1], pooledS, NSOC, 1.f);
    gather2_k<<<grid_w(NC), B, 0, stream>>>(pooledB, rpA, eiA, pooledS, rpB, eiB, agg_a, NC);
    gemm_lds<64, 1, true, TR><<<grid_l(NC), B, 0, stream>>>(cin, L[li][2], agg_a, L[li][3], L[li][4], cout, NC, 2.f);
    float* t = cin; cin = cout; cout = t;
  };
  fwd_layer(0);  // l1f
  fwd_layer(2);  // l2f

  // ---- CSR by source (var / soc) ----------------------------------------
  build_csr(vc_src, vc_dst, EVC, NV, rpA, eiA);
  build_csr(sc_src, sc_dst, ESC, NSOC, rpB, eiB);

  // ---- backward half-passes (update var & soc from final h_con) ---------
  float* vin = h_var;  float* vout = h_var2;
  float* sin_ = h_soc; float* sout = h_soc2;
  auto bwd_layer = [&](int li) {
    gemm_lds<64, 0, true, TR><<<grid_l(NC), B, 0, stream>>>(cin, L[li][0], nullptr, nullptr, L[li][1], pooledB, NC, 1.f);
    gather_max_k<<<grid_w(NV), B, 0, stream>>>(pooledB, rpA, eiA, agg_a, NV);
    gather_max_k<<<grid_w(NSOC), B, 0, stream>>>(pooledB, rpB, eiB, agg_b, NSOC);
    gemm_lds<64, 1, true, TR><<<grid_l(NV), B, 0, stream>>>(vin, L[li][2], agg_a, L[li][3], L[li][4], vout, NV, 1.f);
    gemm_lds<64, 1, true, TR><<<grid_l(NSOC), B, 0, stream>>>(sin_, L[li][2], agg_b, L[li][3], L[li][4], sout, NSOC, 1.f);
    float* t = vin; vin = vout; vout = t;
    t = sin_; sin_ = sout; sout = t;
  };
  bwd_layer(1);  // l1b
  bwd_layer(3);  // l2b

  // ---- fused output MLP -------------------------------------------------
  mlp_k<TR><<<grid_l(NV), B, 0, stream>>>(vin, W_hid, b_hid, W_out, b_out, (float*)d_out, NV);
}